// Round 1
// baseline (664.022 us; speedup 1.0000x reference)
//
#include <hip/hip_runtime.h>
#include <math.h>

#define BB 8
#define CC 64
#define HH 256
#define WW 256
#define NN (HH*WW)          // 65536
#define LDS_STRIDE 68       // 68 floats = 272 B: 16B-aligned rows, 8-way bank conflict only on store phase

// ---------------------------------------------------------------------------
// Stage 1: corr[b,p,q] = sum_{j,i} X[b,p,j,i] * Y[b,q,j,i]
//          Y[b,q,j,i] = w0(i)*X[b,q,j,k0(i)] + w1(i)*X[b,q,j,k1(i)]
// One block per (row j, batch b). 256 threads, 4x4 corr patch per thread.
// ---------------------------------------------------------------------------
__global__ __launch_bounds__(256, 2)
void corr_kernel(const float* __restrict__ x, const int* __restrict__ angle_p,
                 float* __restrict__ corr) {
    __shared__ float  Xs[WW][LDS_STRIDE];
    __shared__ float4 tbl[WW];

    const int j   = blockIdx.x;   // row 0..255
    const int b   = blockIdx.y;   // batch 0..7
    const int tid = threadIdx.x;

    // --- load row j of all 64 channels into LDS (i-major, channel contiguous)
    const float* xb = x + (size_t)(b * CC) * NN + (size_t)j * WW;
    #pragma unroll 8
    for (int c = 0; c < CC; ++c) {
        Xs[tid][c] = xb[(size_t)c * NN + tid];   // coalesced: lanes = consecutive i
    }

    // --- per-i warp table (i = tid), exactly mirroring the reference fp32 math
    {
        const double a  = (double)(*angle_p);
        const float  cf = (float)cos(a);
        const float  sf = (float)sin(a);
        const int i = tid;
        const float gx    = (2.0f * (float)i + 1.0f) / 256.0f - 1.0f; // exact
        const float gridx = cf * gx;            // einsum: c*gx + 0 + s*0 + 0
        const float gridz = (-sf) * gx;
        const float ix = ((gridx + 1.0f) * 256.0f - 1.0f) * 0.5f;
        const float t1 = (gridz + 1.0f);        // *D with D=1
        const float iz = (t1 - 1.0f) * 0.5f;
        const float ix0f = floorf(ix), iz0f = floorf(iz);
        const float fx = ix - ix0f,    fz = iz - iz0f;
        const int   ix0 = (int)ix0f,   iz0 = (int)iz0f;
        float wz = 0.0f;
        if (iz0 ==  0) wz += 1.0f - fz;   // dz=0 corner valid (zi=0)
        if (iz0 == -1) wz += fz;          // dz=1 corner valid (zi=0)
        float w0 = (1.0f - fx) * wz;      // matches ref mul order: (wx*1)*wz
        float w1 = fx * wz;
        int k0 = ix0, k1 = ix0 + 1;
        if (k0 < 0 || k0 >= WW) { w0 = 0.0f; k0 = 0; }   // zeros padding
        if (k1 < 0 || k1 >= WW) { w1 = 0.0f; k1 = 0; }
        tbl[i] = make_float4(w0, w1, __int_as_float(k0), __int_as_float(k1));
    }
    __syncthreads();

    // --- accumulate 4x4 patch: p = 4*ty+r (plain), q = 4*tx+s (warped)
    const int tx = tid & 15;
    const int ty = tid >> 4;
    float acc[4][4];
    #pragma unroll
    for (int r = 0; r < 4; ++r)
        #pragma unroll
        for (int s = 0; s < 4; ++s) acc[r][s] = 0.0f;

    for (int i = 0; i < WW; ++i) {
        const float4 t = tbl[i];                             // LDS broadcast
        const int k0 = __float_as_int(t.z);
        const int k1 = __float_as_int(t.w);
        const float4 xp = *(const float4*)&Xs[i][4 * ty];
        const float4 qa = *(const float4*)&Xs[k0][4 * tx];
        const float4 qb = *(const float4*)&Xs[k1][4 * tx];
        float4 y;
        y.x = fmaf(t.y, qb.x, t.x * qa.x);
        y.y = fmaf(t.y, qb.y, t.x * qa.y);
        y.z = fmaf(t.y, qb.z, t.x * qa.z);
        y.w = fmaf(t.y, qb.w, t.x * qa.w);
        const float xpv[4] = {xp.x, xp.y, xp.z, xp.w};
        const float yv[4]  = {y.x, y.y, y.z, y.w};
        #pragma unroll
        for (int r = 0; r < 4; ++r)
            #pragma unroll
            for (int s = 0; s < 4; ++s)
                acc[r][s] = fmaf(xpv[r], yv[s], acc[r][s]);
    }

    float* cb = corr + (size_t)b * CC * CC;
    #pragma unroll
    for (int r = 0; r < 4; ++r)
        #pragma unroll
        for (int s = 0; s < 4; ++s)
            atomicAdd(&cb[(4 * ty + r) * CC + (4 * tx + s)], acc[r][s]);
}

// ---------------------------------------------------------------------------
// Stage 2: softmax over dim=1 (rows i) per column j; store transposed:
//          proT[b][j][i] = softmax_i(corr[b,:,j])[i]
// ---------------------------------------------------------------------------
__global__ void softmax_kernel(const float* __restrict__ corr,
                               float* __restrict__ proT) {
    const int b  = blockIdx.x;
    const int jj = threadIdx.x;   // column j, 0..63
    const float* cb = corr + (size_t)b * CC * CC;
    float v[CC];
    float m = -1e30f;
    #pragma unroll
    for (int i = 0; i < CC; ++i) {
        v[i] = cb[i * CC + jj];
        m = fmaxf(m, v[i]);
    }
    float ssum = 0.0f;
    #pragma unroll
    for (int i = 0; i < CC; ++i) {
        v[i] = expf(v[i] - m);
        ssum += v[i];
    }
    const float inv = 1.0f / ssum;
    float* pb = proT + (size_t)b * CC * CC + (size_t)jj * CC;
    #pragma unroll
    for (int i = 0; i < CC; ++i) pb[i] = v[i] * inv;
}

// ---------------------------------------------------------------------------
// Stage 3: out[b,p,n] = sum_q pro[b,p,q] * x[b,q,n]
// One block per (b, 256-column chunk). 256 threads: lane = n/4 group (float4),
// wave id = p-group (16 p each) -> all LDS reads are wave-uniform broadcasts.
// ---------------------------------------------------------------------------
__global__ __launch_bounds__(256, 4)
void apply_kernel(const float* __restrict__ x, const float* __restrict__ proT,
                  float* __restrict__ out) {
    __shared__ float P[CC * CC];   // P[q*64 + p] = pro[p][q]
    const int b  = blockIdx.y;
    const int n0 = blockIdx.x * 256;
    const int tid = threadIdx.x;
    for (int t = tid; t < CC * CC; t += 256)
        P[t] = proT[(size_t)b * CC * CC + t];
    __syncthreads();

    const int lane = tid & 63;
    const int pg   = tid >> 6;     // wave index == p-group
    const float* xb = x + (size_t)b * CC * NN + n0 + 4 * lane;

    float4 acc[16];
    #pragma unroll
    for (int r = 0; r < 16; ++r) acc[r] = make_float4(0.f, 0.f, 0.f, 0.f);

    float4 xv = *(const float4*)xb;   // q = 0
    for (int q = 0; q < CC; ++q) {
        float4 xn = make_float4(0.f, 0.f, 0.f, 0.f);
        if (q + 1 < CC) xn = *(const float4*)(xb + (size_t)(q + 1) * NN);
        const float4* pr4 = (const float4*)&P[q * CC + pg * 16];
        const float4 pa = pr4[0], pbv = pr4[1], pc = pr4[2], pd = pr4[3];
        const float pv[16] = {pa.x, pa.y, pa.z, pa.w, pbv.x, pbv.y, pbv.z, pbv.w,
                              pc.x, pc.y, pc.z, pc.w, pd.x, pd.y, pd.z, pd.w};
        #pragma unroll
        for (int r = 0; r < 16; ++r) {
            acc[r].x = fmaf(pv[r], xv.x, acc[r].x);
            acc[r].y = fmaf(pv[r], xv.y, acc[r].y);
            acc[r].z = fmaf(pv[r], xv.z, acc[r].z);
            acc[r].w = fmaf(pv[r], xv.w, acc[r].w);
        }
        xv = xn;
    }

    float* ob = out + (size_t)b * CC * NN + n0 + 4 * lane;
    #pragma unroll
    for (int r = 0; r < 16; ++r)
        *(float4*)(ob + (size_t)(pg * 16 + r) * NN) = acc[r];
}

// ---------------------------------------------------------------------------
extern "C" void kernel_launch(void* const* d_in, const int* in_sizes, int n_in,
                              void* d_out, int out_size, void* d_ws, size_t ws_size,
                              hipStream_t stream) {
    const float* x     = (const float*)d_in[0];
    const int*   angle = (const int*)d_in[1];
    float*       out   = (float*)d_out;

    float* corr = (float*)d_ws;                  // [8][64][64]
    float* proT = corr + (size_t)BB * CC * CC;   // [8][64(j)][64(i)]

    hipMemsetAsync(d_ws, 0, (size_t)BB * CC * CC * sizeof(float), stream);

    corr_kernel<<<dim3(HH, BB), 256, 0, stream>>>(x, angle, corr);
    softmax_kernel<<<dim3(BB), dim3(CC), 0, stream>>>(corr, proT);
    apply_kernel<<<dim3(NN / 256, BB), 256, 0, stream>>>(x, proT, out);
}

// Round 3
// 611.507 us; speedup vs baseline: 1.0859x; 1.0859x over previous
//
#include <hip/hip_runtime.h>
#include <math.h>

#define BB 8
#define CC 64
#define HH 256
#define WW 256
#define NN (HH*WW)          // 65536
#define LDS_STRIDE 68       // 272 B rows: 16B-aligned; all compute reads are single-row -> <=2-way conflicts

typedef float v4f __attribute__((ext_vector_type(4)));   // native vec for NT stores

// ---------------------------------------------------------------------------
// Stage 1: corr[b,p,q] = sum_{j,i} X[b,p,j,i] * Y[b,q,j,i]
//          Y[b,q,j,i] = w0(i)*X[b,q,j,k0(i)] + w1(i)*X[b,q,j,k1(i)]
// One block per (row j, batch b). 512 threads = two 256-thread groups, each
// covering half the i range with a 4x4 corr patch per thread.
// ---------------------------------------------------------------------------
__global__ __launch_bounds__(512, 4)
void corr_kernel(const float* __restrict__ x, const int* __restrict__ angle_p,
                 float* __restrict__ corr) {
    __shared__ float  Xs[WW][LDS_STRIDE];
    __shared__ float4 tbl[WW];

    const int j   = blockIdx.x;   // row 0..255
    const int b   = blockIdx.y;   // batch 0..7
    const int tid = threadIdx.x;  // 0..511

    // --- load row j of all 64 channels into LDS (i-major, channel contiguous)
    const float* xb = x + (size_t)(b * CC) * NN + (size_t)j * WW;
    {
        const int i  = tid & 255;
        const int c0 = (tid >> 8) * 32;
        #pragma unroll 8
        for (int cc = 0; cc < 32; ++cc) {
            Xs[i][c0 + cc] = xb[(size_t)(c0 + cc) * NN + i];
        }
    }

    // --- per-i table, exactly mirroring the reference fp32 math
    if (tid < 256) {
        const double a  = (double)(*angle_p);
        const float  cf = (float)cos(a);
        const float  sf = (float)sin(a);
        const int i = tid;
        const float gx    = (2.0f * (float)i + 1.0f) / 256.0f - 1.0f; // exact
        const float gridx = cf * gx;
        const float gridz = (-sf) * gx;
        const float ix = ((gridx + 1.0f) * 256.0f - 1.0f) * 0.5f;
        const float t1 = (gridz + 1.0f);        // *D with D=1
        const float iz = (t1 - 1.0f) * 0.5f;
        const float ix0f = floorf(ix), iz0f = floorf(iz);
        const float fx = ix - ix0f,    fz = iz - iz0f;
        const int   ix0 = (int)ix0f,   iz0 = (int)iz0f;
        float wz = 0.0f;
        if (iz0 ==  0) wz += 1.0f - fz;   // dz=0 corner valid (zi=0)
        if (iz0 == -1) wz += fz;          // dz=1 corner valid (zi=0)
        float w0 = (1.0f - fx) * wz;
        float w1 = fx * wz;
        int k0 = ix0, k1 = ix0 + 1;
        if (k0 < 0 || k0 >= WW) { w0 = 0.0f; k0 = 0; }   // zeros padding
        if (k1 < 0 || k1 >= WW) { w1 = 0.0f; k1 = 0; }
        tbl[i] = make_float4(w0, w1, __int_as_float(k0), __int_as_float(k1));
    }
    __syncthreads();

    // --- each 256-thread group covers 128 i's; 4x4 patch per thread
    const int t  = tid & 255;
    const int g  = tid >> 8;          // 0 or 1
    const int i0 = g * 128;
    const int tx = t & 15;
    const int ty = t >> 4;

    float acc[4][4];
    #pragma unroll
    for (int r = 0; r < 4; ++r)
        #pragma unroll
        for (int s = 0; s < 4; ++s) acc[r][s] = 0.0f;

    // software pipeline: tbl entries prefetched 2 iterations ahead
    float4 t0 = tbl[i0];
    float4 t1 = tbl[i0 + 1];
    for (int i = i0; i < i0 + 128; i += 2) {
        const float4 tn0 = tbl[(i + 2) & 255];   // mask keeps LDS access in-range
        const float4 tn1 = tbl[(i + 3) & 255];

        const int k0a = __float_as_int(t0.z), k1a = __float_as_int(t0.w);
        const int k0b = __float_as_int(t1.z), k1b = __float_as_int(t1.w);

        const float4 xpa = *(const float4*)&Xs[i][4 * ty];
        const float4 qaa = *(const float4*)&Xs[k0a][4 * tx];
        const float4 qba = *(const float4*)&Xs[k1a][4 * tx];
        const float4 xpb = *(const float4*)&Xs[i + 1][4 * ty];
        const float4 qab = *(const float4*)&Xs[k0b][4 * tx];
        const float4 qbb = *(const float4*)&Xs[k1b][4 * tx];

        float4 ya, yb;
        ya.x = fmaf(t0.y, qba.x, t0.x * qaa.x);
        ya.y = fmaf(t0.y, qba.y, t0.x * qaa.y);
        ya.z = fmaf(t0.y, qba.z, t0.x * qaa.z);
        ya.w = fmaf(t0.y, qba.w, t0.x * qaa.w);
        yb.x = fmaf(t1.y, qbb.x, t1.x * qab.x);
        yb.y = fmaf(t1.y, qbb.y, t1.x * qab.y);
        yb.z = fmaf(t1.y, qbb.z, t1.x * qab.z);
        yb.w = fmaf(t1.y, qbb.w, t1.x * qab.w);

        const float xpav[4] = {xpa.x, xpa.y, xpa.z, xpa.w};
        const float yav[4]  = {ya.x, ya.y, ya.z, ya.w};
        const float xpbv[4] = {xpb.x, xpb.y, xpb.z, xpb.w};
        const float ybv[4]  = {yb.x, yb.y, yb.z, yb.w};
        #pragma unroll
        for (int r = 0; r < 4; ++r)
            #pragma unroll
            for (int s = 0; s < 4; ++s) {
                acc[r][s] = fmaf(xpav[r], yav[s], acc[r][s]);
                acc[r][s] = fmaf(xpbv[r], ybv[s], acc[r][s]);
            }
        t0 = tn0;
        t1 = tn1;
    }

    float* cb = corr + (size_t)b * CC * CC;
    #pragma unroll
    for (int r = 0; r < 4; ++r)
        #pragma unroll
        for (int s = 0; s < 4; ++s)
            atomicAdd(&cb[(4 * ty + r) * CC + (4 * tx + s)], acc[r][s]);
}

// ---------------------------------------------------------------------------
// Stage 2: softmax over dim=1 (rows i) per column j; store transposed:
//          proT[b][j][i] = softmax_i(corr[b,:,j])[i]
// ---------------------------------------------------------------------------
__global__ void softmax_kernel(const float* __restrict__ corr,
                               float* __restrict__ proT) {
    const int b  = blockIdx.x;
    const int jj = threadIdx.x;   // column j, 0..63
    const float* cb = corr + (size_t)b * CC * CC;
    float v[CC];
    float m = -1e30f;
    #pragma unroll
    for (int i = 0; i < CC; ++i) {
        v[i] = cb[i * CC + jj];
        m = fmaxf(m, v[i]);
    }
    float ssum = 0.0f;
    #pragma unroll
    for (int i = 0; i < CC; ++i) {
        v[i] = expf(v[i] - m);
        ssum += v[i];
    }
    const float inv = 1.0f / ssum;
    float* pb = proT + (size_t)b * CC * CC + (size_t)jj * CC;
    #pragma unroll
    for (int i = 0; i < CC; ++i) pb[i] = v[i] * inv;
}

// ---------------------------------------------------------------------------
// Stage 3: out[b,p,n] = sum_q pro[b,p,q] * x[b,q,n]
// One block per (b, 256-col chunk). 4-deep load pipeline; NT stores.
// ---------------------------------------------------------------------------
__global__ __launch_bounds__(256, 4)
void apply_kernel(const float* __restrict__ x, const float* __restrict__ proT,
                  float* __restrict__ out) {
    __shared__ float P[CC * CC];   // P[q*64 + p] = pro[p][q]
    const int b   = blockIdx.y;
    const int n0  = blockIdx.x * 256;
    const int tid = threadIdx.x;
    for (int t = tid; t < CC * CC; t += 256)
        P[t] = proT[(size_t)b * CC * CC + t];
    __syncthreads();

    const int lane = tid & 63;
    const int pg   = tid >> 6;     // wave index == p-group (16 p's each)
    const float* xb = x + (size_t)b * CC * NN + n0 + 4 * lane;

    float4 acc[16];
    #pragma unroll
    for (int r = 0; r < 16; ++r) acc[r] = make_float4(0.f, 0.f, 0.f, 0.f);

    // 4-deep prefetch pipeline: 4 KB in flight per wave
    float4 buf[4];
    #pragma unroll
    for (int u = 0; u < 4; ++u) buf[u] = *(const float4*)(xb + (size_t)u * NN);

    for (int q = 0; q < CC; ++q) {
        const float4 xv = buf[q & 3];
        if (q + 4 < CC) buf[q & 3] = *(const float4*)(xb + (size_t)(q + 4) * NN);

        const float4* pr4 = (const float4*)&P[q * CC + pg * 16];
        const float4 pa = pr4[0], pbv = pr4[1], pc = pr4[2], pd = pr4[3];
        const float pv[16] = {pa.x, pa.y, pa.z, pa.w, pbv.x, pbv.y, pbv.z, pbv.w,
                              pc.x, pc.y, pc.z, pc.w, pd.x, pd.y, pd.z, pd.w};
        #pragma unroll
        for (int r = 0; r < 16; ++r) {
            acc[r].x = fmaf(pv[r], xv.x, acc[r].x);
            acc[r].y = fmaf(pv[r], xv.y, acc[r].y);
            acc[r].z = fmaf(pv[r], xv.z, acc[r].z);
            acc[r].w = fmaf(pv[r], xv.w, acc[r].w);
        }
    }

    float* ob = out + (size_t)b * CC * NN + n0 + 4 * lane;
    #pragma unroll
    for (int r = 0; r < 16; ++r) {
        v4f v = {acc[r].x, acc[r].y, acc[r].z, acc[r].w};
        __builtin_nontemporal_store(v, (v4f*)(ob + (size_t)(pg * 16 + r) * NN));
    }
}

// ---------------------------------------------------------------------------
extern "C" void kernel_launch(void* const* d_in, const int* in_sizes, int n_in,
                              void* d_out, int out_size, void* d_ws, size_t ws_size,
                              hipStream_t stream) {
    const float* x     = (const float*)d_in[0];
    const int*   angle = (const int*)d_in[1];
    float*       out   = (float*)d_out;

    float* corr = (float*)d_ws;                  // [8][64][64]
    float* proT = corr + (size_t)BB * CC * CC;   // [8][64(j)][64(i)]

    (void)hipMemsetAsync(d_ws, 0, (size_t)BB * CC * CC * sizeof(float), stream);

    corr_kernel<<<dim3(HH, BB), 512, 0, stream>>>(x, angle, corr);
    softmax_kernel<<<dim3(BB), dim3(CC), 0, stream>>>(corr, proT);
    apply_kernel<<<dim3(NN / 256, BB), 256, 0, stream>>>(x, proT, out);
}